// Round 1
// baseline (109.410 us; speedup 1.0000x reference)
//
#include <hip/hip_runtime.h>
#include <math.h>

// Problem constants (Occ3D-nuScenes volume)
constexpr int   GX = 200, GY = 200, GZ = 16;
constexpr int   TOTAL = GX * GY * GZ;        // 640000 voxels
constexpr int   ND = 16;                     // feature dims
constexpr int   KW = 6;                      // reference window: start + [0,6)
constexpr float VS = 0.4f;
constexpr float VMINX = -40.0f, VMINY = -40.0f, VMINZ = -1.0f;

// Tiling: 4x4x4 voxel tiles; one WAVE per tile (1 voxel/lane, 17 accumulators).
constexpr int   TS = 4;
constexpr int   TX = 50, TY = 50, TZ = 4;    // 200/4, 200/4, 16/4
constexpr int   NT = TX * TY * TZ;           // 10000 tiles
constexpr int   RS = 20;                     // floats per record (80 B)
constexpr int   CAP = 128;                   // per-tile capacity (lambda~13, max~55)
constexpr float NHL2E = -0.72134752044448170f; // -0.5*log2(e): exp(-0.5*m) -> exp2(q)

// Record layout (floats), 80 B:
//  [0..3]   mx, my, mz, opacity
//  [4..7]   q00, q01*2, q02*2, q11    (inverse cov pre-scaled by NHL2E)
//  [8..11]  q12*2, q22, s_packed, e_packed  (bbox packed 8b/axis)
//  [12..19] features as bf16 (RNE), 2 per uint
// d_out layout: [density: TOTAL floats][feats: TOTAL*ND floats]
// d_ws layout:  [gdata: n*RS floats][counts: NT][entries: NT*CAP]

__device__ __forceinline__ unsigned bf16_rne(float x) {
    unsigned u = __float_as_uint(x);
    return (u + 0x7fffu + ((u >> 16) & 1u)) >> 16;
}

// 64-thread blocks: 512 blocks spread the latency-bound atomic binning across
// all 256 CUs (256-thread blocks left half the CUs idle: 128 blocks).
__global__ __launch_bounds__(64) void gv_prep(
    const float* __restrict__ means, const float* __restrict__ covs,
    const float* __restrict__ opac,  const float* __restrict__ feats,
    float* __restrict__ gdata, int* __restrict__ counts,
    int* __restrict__ entries, int n)
{
    int g = blockIdx.x * 64 + threadIdx.x;
    if (g >= n) return;
    const float* cv = covs + (size_t)g * 9;
    // symmetric 3x3: [[a,b,c],[b,d,e],[c,e,f]]
    float a = cv[0], b = cv[1], c = cv[2], d = cv[4], e = cv[5], f = cv[8];
    float A = d * f - e * e;
    float B = c * e - b * f;
    float C = b * e - c * d;
    float invdet = 1.0f / (a * A + b * B + c * C);
    float mx = means[g * 3 + 0], my = means[g * 3 + 1], mz = means[g * 3 + 2];
    float rx = 3.0f * sqrtf(a), ry = 3.0f * sqrtf(d), rz = 3.0f * sqrtf(f);
    // trunc-toward-zero matches .astype(int32)
    int sx = max(0, (int)((mx - rx - VMINX) / VS));
    int sy = max(0, (int)((my - ry - VMINY) / VS));
    int sz = max(0, (int)((mz - rz - VMINZ) / VS));
    // reference window is start + [0,KW) masked by end -> clamp end to start+KW
    int ex = min(GX, (int)((mx + rx - VMINX) / VS) + 1); ex = min(ex, sx + KW);
    int ey = min(GY, (int)((my + ry - VMINY) / VS) + 1); ey = min(ey, sy + KW);
    int ez = min(GZ, (int)((mz + rz - VMINZ) / VS) + 1); ez = min(ez, sz + KW);

    float rec[RS];
    rec[0] = mx; rec[1] = my; rec[2] = mz; rec[3] = opac[g];
    rec[4] = (A * invdet) * NHL2E;                        // q00
    rec[5] = (B * invdet) * (2.0f * NHL2E);               // q01 (doubled)
    rec[6] = (C * invdet) * (2.0f * NHL2E);               // q02 (doubled)
    rec[7] = ((a * f - c * c) * invdet) * NHL2E;          // q11
    rec[8] = ((b * c - a * e) * invdet) * (2.0f * NHL2E); // q12 (doubled)
    rec[9] = ((a * d - b * b) * invdet) * NHL2E;          // q22
    rec[10] = __int_as_float(sx | (sy << 8) | (sz << 16));
    rec[11] = __int_as_float(ex | (ey << 8) | (ez << 16));
    const float* fr = feats + (size_t)g * ND;
#pragma unroll
    for (int q = 0; q < 8; ++q) {
        unsigned lo = bf16_rne(fr[2 * q]);
        unsigned hi = bf16_rne(fr[2 * q + 1]);
        rec[12 + q] = __uint_as_float(lo | (hi << 16));
    }
    float4* dst = (float4*)(gdata + (size_t)g * RS);   // 80B stride, 16B aligned
#pragma unroll
    for (int q = 0; q < 5; ++q) dst[q] = ((const float4*)rec)[q];

    // 3-D binning at 4^3
    int tx0 = sx >> 2, tx1 = (ex - 1) >> 2;
    int ty0 = sy >> 2, ty1 = (ey - 1) >> 2;
    int tz0 = sz >> 2, tz1 = (ez - 1) >> 2;
    for (int tx = tx0; tx <= tx1; ++tx)
        for (int ty = ty0; ty <= ty1; ++ty)
            for (int tz = tz0; tz <= tz1; ++tz) {
                int tile = (tx * TY + ty) * TZ + tz;
                int slot = atomicAdd(&counts[tile], 1);
                if (slot < CAP) entries[(size_t)tile * CAP + slot] = g;
            }
}

// All record data is wave-uniform -> keep it in SGPRs via scalar (SMEM) loads.
// readfirstlane(p) makes the tile id provably uniform, so counts[], entries[]
// and the 80B records compile to s_load_dwordx4/x8: no LDS, no stager lanes,
// no per-lane VMEM in the loop. Every VALU op reads record fields as SGPR
// operands (1 SGPR/instr); bf16 unpack and bbox unpack run on the SALU pipe,
// overlapped with VALU. 2-deep pipeline: record data prefetched 1 iteration
// ahead, entry ids 2 ahead, so SMEM latency hides under ~90 VALU cycles.
struct RecS {
    float mx, my, mz, op;
    float q00, q01, q02, q11;    // q01,q02 pre-doubled
    float q12, q22;              // q12 pre-doubled
    unsigned spk, epk;
    unsigned f0, f1, f2, f3, f4, f5, f6, f7;
};

__device__ __forceinline__ RecS load_rec(const float* __restrict__ rp) {
    RecS c;
    const float4 a = ((const float4*)rp)[0];
    const float4 b = ((const float4*)rp)[1];
    const float4 d = ((const float4*)rp)[2];
    const uint4  e = ((const uint4*)rp)[3];
    const uint4  f = ((const uint4*)rp)[4];
    c.mx = a.x;  c.my = a.y;  c.mz = a.z;  c.op = a.w;
    c.q00 = b.x; c.q01 = b.y; c.q02 = b.z; c.q11 = b.w;
    c.q12 = d.x; c.q22 = d.y;
    c.spk = __float_as_uint(d.z); c.epk = __float_as_uint(d.w);
    c.f0 = e.x; c.f1 = e.y; c.f2 = e.z; c.f3 = e.w;
    c.f4 = f.x; c.f5 = f.y; c.f6 = f.z; c.f7 = f.w;
    return c;
}

__global__ __launch_bounds__(256) void gv_tile(
    const float* __restrict__ gdata, const int* __restrict__ counts,
    const int* __restrict__ entries, float* __restrict__ out)
{
    const int wv   = threadIdx.x >> 6;
    const int lane = threadIdx.x & 63;
    // readfirstlane -> wave-uniform tile id for the divergence analysis
    const int p    = __builtin_amdgcn_readfirstlane(blockIdx.x * 4 + wv);
    const int tz   = p % TZ;
    const int ty   = (p / TZ) % TY;
    const int tx   = p / (TZ * TY);

    const int lz = lane & 3, ly = (lane >> 2) & 3, lx = lane >> 4;
    const int ix = tx * TS + lx, iy = ty * TS + ly, iz = tz * TS + lz;
    const float pxc = (float)ix * VS + VMINX;   // voxel CORNER coords
    const float pyc = (float)iy * VS + VMINY;
    const float pzc = (float)iz * VS + VMINZ;

    float accd = 0.0f;
    float accf[ND];
#pragma unroll
    for (int c = 0; c < ND; ++c) accf[c] = 0.0f;
    accf[ND - 1] = 1e-5f;                       // reference: grid_feats[:, -1] = 1e-5

    const int cnt = min(counts[p], CAP);        // uniform -> s_load
    const int* __restrict__ el = entries + (size_t)p * CAP;

    if (cnt > 0) {
        int id0 = el[0];                                   // uniform s_load
        RecS cur = load_rec(gdata + (size_t)id0 * RS);
        int idn = el[cnt > 1 ? 1 : 0];
        for (int r = 0; r < cnt; ++r) {
            RecS nxt = load_rec(gdata + (size_t)idn * RS); // prefetch r+1
            idn = el[min(r + 2, cnt - 1)];                 // prefetch id r+2

            // bbox test: SALU unpack (spk/epk in SGPRs) + 3 v_sub + 3 v_cmp
            int sx = cur.spk & 255, sy = (cur.spk >> 8) & 255, sz = (cur.spk >> 16) & 255;
            int ex = cur.epk & 255, ey = (cur.epk >> 8) & 255, ez = (cur.epk >> 16) & 255;
            bool in = ((unsigned)(ix - sx) < (unsigned)(ex - sx))
                    & ((unsigned)(iy - sy) < (unsigned)(ey - sy))
                    & ((unsigned)(iz - sz) < (unsigned)(ez - sz));

            float px = pxc - cur.mx;
            float py = pyc - cur.my;
            float pz = pzc - cur.mz;
            float q = cur.q00 * px * px + cur.q11 * py * py + cur.q22 * pz * pz
                    + cur.q01 * px * py + cur.q02 * px * pz + cur.q12 * py * pz;
            float dens = cur.op * __builtin_amdgcn_exp2f(q);
            dens = in ? dens : 0.0f;
            accd += dens;

            // bf16 features unpacked on the SALU pipe; FMA reads SGPR directly
            accf[0]  = fmaf(dens, __uint_as_float(cur.f0 << 16),         accf[0]);
            accf[1]  = fmaf(dens, __uint_as_float(cur.f0 & 0xffff0000u), accf[1]);
            accf[2]  = fmaf(dens, __uint_as_float(cur.f1 << 16),         accf[2]);
            accf[3]  = fmaf(dens, __uint_as_float(cur.f1 & 0xffff0000u), accf[3]);
            accf[4]  = fmaf(dens, __uint_as_float(cur.f2 << 16),         accf[4]);
            accf[5]  = fmaf(dens, __uint_as_float(cur.f2 & 0xffff0000u), accf[5]);
            accf[6]  = fmaf(dens, __uint_as_float(cur.f3 << 16),         accf[6]);
            accf[7]  = fmaf(dens, __uint_as_float(cur.f3 & 0xffff0000u), accf[7]);
            accf[8]  = fmaf(dens, __uint_as_float(cur.f4 << 16),         accf[8]);
            accf[9]  = fmaf(dens, __uint_as_float(cur.f4 & 0xffff0000u), accf[9]);
            accf[10] = fmaf(dens, __uint_as_float(cur.f5 << 16),         accf[10]);
            accf[11] = fmaf(dens, __uint_as_float(cur.f5 & 0xffff0000u), accf[11]);
            accf[12] = fmaf(dens, __uint_as_float(cur.f6 << 16),         accf[12]);
            accf[13] = fmaf(dens, __uint_as_float(cur.f6 & 0xffff0000u), accf[13]);
            accf[14] = fmaf(dens, __uint_as_float(cur.f7 << 16),         accf[14]);
            accf[15] = fmaf(dens, __uint_as_float(cur.f7 & 0xffff0000u), accf[15]);

            cur = nxt;
        }
    }

    // Epilogue: density (raw) + normalized features; each voxel exactly once.
    const int flat = (ix * GY + iy) * GZ + iz;
    out[flat] = accd;
    float inv = 1.0f / fmaxf(accd, 1e-6f);      // clip(density, 1e-6, None)
    float4* fo = (float4*)(out + TOTAL + (size_t)flat * ND);
#pragma unroll
    for (int q = 0; q < 4; ++q) {
        float4 w;
        w.x = accf[q * 4 + 0] * inv;
        w.y = accf[q * 4 + 1] * inv;
        w.z = accf[q * 4 + 2] * inv;
        w.w = accf[q * 4 + 3] * inv;
        fo[q] = w;
    }
}

extern "C" void kernel_launch(void* const* d_in, const int* in_sizes, int n_in,
                              void* d_out, int out_size, void* d_ws, size_t ws_size,
                              hipStream_t stream) {
    const float* means = (const float*)d_in[0];   // [N,3]
    const float* covs  = (const float*)d_in[1];   // [N,3,3]
    const float* opac  = (const float*)d_in[2];   // [N]
    const float* feats = (const float*)d_in[3];   // [N,16]
    float* out = (float*)d_out;                   // [TOTAL + TOTAL*ND]
    const int n = in_sizes[2];

    float* gdata   = (float*)d_ws;                            // n*RS floats (2.6 MB)
    int*   counts  = (int*)(gdata + (size_t)n * RS);          // NT ints
    int*   entries = counts + ((NT + 63) & ~63);              // NT*CAP ints (5.12 MB)

    hipMemsetAsync(counts, 0, NT * sizeof(int), stream);
    gv_prep<<<(n + 63) / 64, 64, 0, stream>>>(means, covs, opac, feats,
                                              gdata, counts, entries, n);
    gv_tile<<<NT / 4, 256, 0, stream>>>(gdata, counts, entries, out);
}